// Round 7
// baseline (134.515 us; speedup 1.0000x reference)
//
#include <hip/hip_runtime.h>
#include <hip/hip_fp16.h>

#define D_ 160
#define H_ 192
#define W_ 160
#define PLANE (H_*W_)          // 30720
#define VOL (D_*PLANE)         // 4915200 per sample (per quantity)
#define NS 2
#define WSZ 729.0f
#define DC 5                   // d-outputs per k_d thread

// B per sample: 5 quantities (I, J, I*I, J*J, I*J), each VOL fp16,
// layout [q][h][d][w]  <-- d is the SECOND-minor axis: a 9-deep d-window
// spans only 9*320B, so k_d's sliding-window re-reads stay L1/L2-hot.

__global__ void k_zero(float* acc) {
    if (threadIdx.x < NS) acc[threadIdx.x] = 0.f;
}

// ---------------- pass 1: products + W-sum + H-sum -> fp16 B ----------------
// thread: 8 w (seg) x 8 h-outputs (chunk) x fixed d.  (r4 structure, new layout)
// per sample: seg(20) x chunk(24) x d(160) = 76800 threads = 300 blocks
__global__ __launch_bounds__(256) void k_wh(const float* __restrict__ I,
                                            const float* __restrict__ J,
                                            __half* __restrict__ B, long stride) {
    int b  = blockIdx.x;
    int sl = b / 300;
    int t  = (b % 300) * 256 + threadIdx.x;     // 0..76799
    int seg   = t % 20;
    int chunk = (t / 20) % 24;
    int d     = t / 480;                        // 0..159
    int w0 = seg * 8;
    int h0 = chunk * 8;
    const float* Ib = I + (long)sl * VOL + (long)d * PLANE;
    const float* Jb = J + (long)sl * VOL + (long)d * PLANE;
    // output base at (q=0, h=0, d, w0); h advances by D_*W_, q by VOL
    __half* Bb = B + (long)sl * stride + (long)d * W_ + w0;

    float rs[5][8];
#pragma unroll
    for (int q = 0; q < 5; ++q)
#pragma unroll
        for (int k = 0; k < 8; ++k) rs[q][k] = 0.f;

    auto rowop = [&](int h, float sign) {
        if (h < 0 || h >= H_) return;
        const float* ri = Ib + (long)h * W_;
        const float* rj = Jb + (long)h * W_;
        float vI[16], vJ[16];
#pragma unroll
        for (int bq = 0; bq < 4; ++bq) {
            int f0 = w0 - 4 + 4 * bq;           // multiple of 4 -> aligned
            if (f0 >= 0 && f0 <= W_ - 4) {
                float4 a = *reinterpret_cast<const float4*>(ri + f0);
                float4 c = *reinterpret_cast<const float4*>(rj + f0);
                vI[4*bq+0]=a.x; vI[4*bq+1]=a.y; vI[4*bq+2]=a.z; vI[4*bq+3]=a.w;
                vJ[4*bq+0]=c.x; vJ[4*bq+1]=c.y; vJ[4*bq+2]=c.z; vJ[4*bq+3]=c.w;
            } else {
#pragma unroll
                for (int k = 0; k < 4; ++k) { vI[4*bq+k] = 0.f; vJ[4*bq+k] = 0.f; }
            }
        }
#pragma unroll
        for (int q = 0; q < 5; ++q) {
            float p[16];
#pragma unroll
            for (int i = 0; i < 16; ++i) {
                float a = vI[i], bb = vJ[i];
                p[i] = (q == 0) ? a : (q == 1) ? bb : (q == 2) ? a*a : (q == 3) ? bb*bb : a*bb;
            }
            float o[8];
            float ssum = 0.f;
#pragma unroll
            for (int i = 0; i < 9; ++i) ssum += p[i];
            o[0] = ssum;
#pragma unroll
            for (int k = 1; k < 8; ++k) { ssum += p[k + 8] - p[k - 1]; o[k] = ssum; }
#pragma unroll
            for (int k = 0; k < 8; ++k) rs[q][k] += sign * o[k];
        }
    };

    // init window rows [h0-4, h0+3]
    for (int i = 0; i < 8; ++i) rowop(h0 - 4 + i, 1.f);

    for (int hh = 0; hh < 8; ++hh) {
        int h = h0 + hh;
        rowop(h + 4, 1.f);                       // window now [h-4, h+4]
#pragma unroll
        for (int q = 0; q < 5; ++q) {
            union { __half hv[8]; int4 v; } u;
#pragma unroll
            for (int k = 0; k < 8; ++k) u.hv[k] = __float2half(rs[q][k]);
            *reinterpret_cast<int4*>(Bb + (long)q * VOL + (long)h * (D_ * W_)) = u.v;
        }
        rowop(h - 4, -1.f);                      // prep next: [h-3, h+4]
    }
}

// ---------------- pass 2: D-axis 9-box-sum + cc + reduction ----------------
// thread: 8 consecutive w (int4 loads), fixed h, d-chunk of DC=5.
// With [q][h][d][w] layout each thread's whole working set per q is a
// compact (DC+9)*320B run -> recompute-subtract re-reads are L1/L2-hot.
// per sample: ws(20) x h(192) x chunk(32) = 122880 threads = 480 blocks
__device__ __forceinline__ float ccf(float Is, float Js, float I2, float J2, float IJ) {
    float uI = Is * (1.f / WSZ), uJ = Js * (1.f / WSZ);
    float cross = IJ - uJ * Is - uI * Js + uI * uJ * WSZ;
    float Iv = I2 - 2.f * uI * Is + uI * uI * WSZ;
    float Jv = J2 - 2.f * uJ * Js + uJ * uJ * WSZ;
    return 1.f - cross * cross / (Iv * Jv + 1e-5f);
}

__global__ __launch_bounds__(256) void k_d(const __half* __restrict__ B,
                                           float* __restrict__ acc, long stride) {
    int b  = blockIdx.x;
    int sl = b / 480;
    int t  = (b % 480) * 256 + threadIdx.x;     // 0..122879
    int ws    = t % 20;
    int h     = (t / 20) % 192;
    int chunk = t / 3840;                       // 0..31
    int d0 = chunk * DC;
    const __half* Bb = B + (long)sl * stride + (long)h * (D_ * W_) + ws * 8;  // + q*VOL + d*W_

    float s[5][8];
#pragma unroll
    for (int q = 0; q < 5; ++q)
#pragma unroll
        for (int k = 0; k < 8; ++k) s[q][k] = 0.f;

    auto plane = [&](float (&sq)[8], int q, int d, float sign) {
        if (d < 0 || d >= D_) return;
        union { __half hv[8]; int4 v; } u;
        u.v = *reinterpret_cast<const int4*>(Bb + (long)q * VOL + (long)d * W_);
#pragma unroll
        for (int k = 0; k < 8; ++k) sq[k] += sign * __half2float(u.hv[k]);
    };

    // init window [d0-4, d0+4]
#pragma unroll
    for (int q = 0; q < 5; ++q)
#pragma unroll
        for (int i = -4; i <= 4; ++i) plane(s[q], q, d0 + i, 1.f);

    float local = 0.f;
#pragma unroll
    for (int dd = 0; dd < DC; ++dd) {
#pragma unroll
        for (int k = 0; k < 8; ++k)
            local += ccf(s[0][k], s[1][k], s[2][k], s[3][k], s[4][k]);
        int da = d0 + dd + 5, dsu = d0 + dd - 4;
#pragma unroll
        for (int q = 0; q < 5; ++q) { plane(s[q], q, da, 1.f); plane(s[q], q, dsu, -1.f); }
    }

    __shared__ float red[256];
    red[threadIdx.x] = local;
    __syncthreads();
    for (int off = 128; off > 0; off >>= 1) {
        if (threadIdx.x < off) red[threadIdx.x] += red[threadIdx.x + off];
        __syncthreads();
    }
    if (threadIdx.x == 0) atomicAdd(acc + sl, red[0]);
}

__global__ void k_fin(const float* __restrict__ acc, float* __restrict__ out) {
    if (threadIdx.x < NS) out[threadIdx.x] = acc[threadIdx.x] * (1.f / (float)VOL);
}

extern "C" void kernel_launch(void* const* d_in, const int* in_sizes, int n_in,
                              void* d_out, int out_size, void* d_ws, size_t ws_size,
                              hipStream_t stream) {
    const float* J = (const float*)d_in[0];   // y_pred
    const float* I = (const float*)d_in[1];   // y_true
    float* out = (float*)d_out;
    __half* B  = (__half*)d_ws;               // 2 samples x 5*VOL fp16 = 98.3 MB

    const long SAMP = 5L * VOL;
    float* acc = (float*)((char*)d_ws + (size_t)(NS * SAMP) * sizeof(__half));

    k_zero<<<1, 64, 0, stream>>>(acc);
    k_wh<<<NS * 300, 256, 0, stream>>>(I, J, B, SAMP);
    k_d<<<NS * 480, 256, 0, stream>>>(B, acc, SAMP);
    k_fin<<<1, 64, 0, stream>>>(acc, out);
}

// Round 8
// 120.834 us; speedup vs baseline: 1.1132x; 1.1132x over previous
//
#include <hip/hip_runtime.h>
#include <hip/hip_fp16.h>

#define D_ 160
#define H_ 192
#define W_ 160
#define PLANE (H_*W_)          // 30720
#define VOL (D_*PLANE)         // 4915200 per sample (per quantity)
#define NS 2
#define WSZ 729.0f
#define DC 10                  // d-outputs per k_d thread

// B per sample: 5 quantities (I, J, I*I, J*J, I*J), each VOL fp16,
// layout [q][d][h][w] (r4 layout: k_d threads share d-planes -> L2/L3 reuse)

__global__ void k_zero(float* acc) {
    if (threadIdx.x < NS) acc[threadIdx.x] = 0.f;
}

// ---------------- pass 1: products + W-sum + H-sum -> fp16 B ----------------
// thread: 4 w (seg) x 8 h-outputs (chunk) x fixed d.
// vs r4: w-seg halved 8->4. Same rowops/output (3.0), same rows touched
// (FETCH unchanged, tap overlap is L1-hot), half the register state,
// 2x thread count -> 1200 blocks.
// per sample: seg(40) x chunk(24) x d(160) = 307200 threads = 600 blocks... wait:
// 40*24*160 = 153600 threads = 600 blocks/sample, 1200 total.
__global__ __launch_bounds__(256) void k_wh(const float* __restrict__ I,
                                            const float* __restrict__ J,
                                            __half* __restrict__ B, long stride) {
    int b  = blockIdx.x;
    int sl = b / 600;
    int t  = (b % 600) * 256 + threadIdx.x;     // 0..153599
    int seg   = t % 40;
    int chunk = (t / 40) % 24;
    int d     = t / 960;                        // 0..159
    int w0 = seg * 4;
    int h0 = chunk * 8;
    const float* Ib = I + (long)sl * VOL + (long)d * PLANE;
    const float* Jb = J + (long)sl * VOL + (long)d * PLANE;
    __half* Bb = B + (long)sl * stride + (long)d * PLANE + w0;   // + q*VOL + h*W_

    float rs[5][4];
#pragma unroll
    for (int q = 0; q < 5; ++q)
#pragma unroll
        for (int k = 0; k < 4; ++k) rs[q][k] = 0.f;

    // one row's W-window sums (4 outputs) for all 5 quantities, signed accumulate
    auto rowop = [&](int h, float sign) {
        if (h < 0 || h >= H_) return;
        const float* ri = Ib + (long)h * W_;
        const float* rj = Jb + (long)h * W_;
        float vI[12], vJ[12];
#pragma unroll
        for (int bq = 0; bq < 3; ++bq) {
            int f0 = w0 - 4 + 4 * bq;           // multiple of 4 -> aligned
            if (f0 >= 0 && f0 <= W_ - 4) {
                float4 a = *reinterpret_cast<const float4*>(ri + f0);
                float4 c = *reinterpret_cast<const float4*>(rj + f0);
                vI[4*bq+0]=a.x; vI[4*bq+1]=a.y; vI[4*bq+2]=a.z; vI[4*bq+3]=a.w;
                vJ[4*bq+0]=c.x; vJ[4*bq+1]=c.y; vJ[4*bq+2]=c.z; vJ[4*bq+3]=c.w;
            } else {
#pragma unroll
                for (int k = 0; k < 4; ++k) { vI[4*bq+k] = 0.f; vJ[4*bq+k] = 0.f; }
            }
        }
#pragma unroll
        for (int q = 0; q < 5; ++q) {
            float p[12];
#pragma unroll
            for (int i = 0; i < 12; ++i) {
                float a = vI[i], bb = vJ[i];
                p[i] = (q == 0) ? a : (q == 1) ? bb : (q == 2) ? a*a : (q == 3) ? bb*bb : a*bb;
            }
            float o[4];
            float ssum = 0.f;
#pragma unroll
            for (int i = 0; i < 9; ++i) ssum += p[i];
            o[0] = ssum;
#pragma unroll
            for (int k = 1; k < 4; ++k) { ssum += p[k + 8] - p[k - 1]; o[k] = ssum; }
#pragma unroll
            for (int k = 0; k < 4; ++k) rs[q][k] += sign * o[k];
        }
    };

    // init window rows [h0-4, h0+3]
    for (int i = 0; i < 8; ++i) rowop(h0 - 4 + i, 1.f);

    for (int hh = 0; hh < 8; ++hh) {
        int h = h0 + hh;
        rowop(h + 4, 1.f);                       // window now [h-4, h+4]
#pragma unroll
        for (int q = 0; q < 5; ++q) {
            union { __half hv[4]; uint2 v; } u;
#pragma unroll
            for (int k = 0; k < 4; ++k) u.hv[k] = __float2half(rs[q][k]);
            *reinterpret_cast<uint2*>(Bb + (long)q * VOL + (long)h * W_) = u.v;  // 8B store
        }
        rowop(h - 4, -1.f);                      // prep next: [h-3, h+4]
    }
}

// ---------------- pass 2: D-axis 9-box-sum + cc + reduction ----------------
// thread: 4 consecutive w (uint2 loads), fixed h, d-chunk of DC=10.
// No ring: slide via add(d+4)/sub(d-5) re-loads (L2/L3-hot, exact cancel).
// per sample: ws(40) x h(192) x chunk(16) = 122880 threads = 480 blocks
__device__ __forceinline__ float ccf(float Is, float Js, float I2, float J2, float IJ) {
    float uI = Is * (1.f / WSZ), uJ = Js * (1.f / WSZ);
    float cross = IJ - uJ * Is - uI * Js + uI * uJ * WSZ;
    float Iv = I2 - 2.f * uI * Is + uI * uI * WSZ;
    float Jv = J2 - 2.f * uJ * Js + uJ * uJ * WSZ;
    return 1.f - cross * cross / (Iv * Jv + 1e-5f);
}

__global__ __launch_bounds__(256) void k_d(const __half* __restrict__ B,
                                           float* __restrict__ acc, long stride) {
    int b  = blockIdx.x;
    int sl = b / 480;
    int t  = (b % 480) * 256 + threadIdx.x;     // 0..122879
    int ws    = t % 40;
    int h     = (t / 40) % 192;
    int chunk = t / 7680;                       // 0..15
    int d0 = chunk * DC;
    const __half* Bb = B + (long)sl * stride + (long)h * W_ + ws * 4;  // + q*VOL + d*PLANE

    float s[5][4];
#pragma unroll
    for (int q = 0; q < 5; ++q)
#pragma unroll
        for (int k = 0; k < 4; ++k) s[q][k] = 0.f;

    auto plane = [&](float (&sq)[4], int q, int d, float sign) {
        if (d < 0 || d >= D_) return;
        union { __half hv[4]; uint2 v; } u;
        u.v = *reinterpret_cast<const uint2*>(Bb + (long)q * VOL + (long)d * PLANE);
#pragma unroll
        for (int k = 0; k < 4; ++k) sq[k] += sign * __half2float(u.hv[k]);
    };

    // init window [d0-4, d0+4]
#pragma unroll
    for (int q = 0; q < 5; ++q)
#pragma unroll
        for (int i = -4; i <= 4; ++i) plane(s[q], q, d0 + i, 1.f);

    float local = 0.f;
    for (int dd = 0; dd < DC; ++dd) {
#pragma unroll
        for (int k = 0; k < 4; ++k)
            local += ccf(s[0][k], s[1][k], s[2][k], s[3][k], s[4][k]);
        int da = d0 + dd + 5, dsu = d0 + dd - 4;
#pragma unroll
        for (int q = 0; q < 5; ++q) { plane(s[q], q, da, 1.f); plane(s[q], q, dsu, -1.f); }
    }

    __shared__ float red[256];
    red[threadIdx.x] = local;
    __syncthreads();
    for (int off = 128; off > 0; off >>= 1) {
        if (threadIdx.x < off) red[threadIdx.x] += red[threadIdx.x + off];
        __syncthreads();
    }
    if (threadIdx.x == 0) atomicAdd(acc + sl, red[0]);
}

__global__ void k_fin(const float* __restrict__ acc, float* __restrict__ out) {
    if (threadIdx.x < NS) out[threadIdx.x] = acc[threadIdx.x] * (1.f / (float)VOL);
}

extern "C" void kernel_launch(void* const* d_in, const int* in_sizes, int n_in,
                              void* d_out, int out_size, void* d_ws, size_t ws_size,
                              hipStream_t stream) {
    const float* J = (const float*)d_in[0];   // y_pred
    const float* I = (const float*)d_in[1];   // y_true
    float* out = (float*)d_out;
    __half* B  = (__half*)d_ws;               // 2 samples x 5*VOL fp16 = 98.3 MB

    const long SAMP = 5L * VOL;
    float* acc = (float*)((char*)d_ws + (size_t)(NS * SAMP) * sizeof(__half));

    k_zero<<<1, 64, 0, stream>>>(acc);
    k_wh<<<NS * 600, 256, 0, stream>>>(I, J, B, SAMP);
    k_d<<<NS * 480, 256, 0, stream>>>(B, acc, SAMP);
    k_fin<<<1, 64, 0, stream>>>(acc, out);
}